// Round 14
// baseline (68.124 us; speedup 1.0000x reference)
//
#include <hip/hip_runtime.h>

#define LN_EPS 1e-5f

typedef __fp16 h2 __attribute__((ext_vector_type(2)));

static constexpr int Hc  = 512;
static constexpr int Fc  = 16;
static constexpr int Sc  = 1024;
static constexpr int RPW = 16;       // rows per wave: same s, consecutive b

// ---- prologue: bsum[h] = sum_i b[i][h] (512 floats into d_ws) ----
__global__ void bsum_kernel(const float* __restrict__ b, float* __restrict__ bsum) {
    int h = blockIdx.x * 64 + threadIdx.x;
    float s = 0.f;
#pragma unroll
    for (int i = 0; i < Fc; ++i) s += b[i * Hc + h];
    bsum[h] = s;
}

// ---- DPP wave64 sum: 6 VALU steps + readlane, no LDS, no barriers ----
template <int CTRL, int RMASK>
__device__ __forceinline__ float dpp_add(float v) {
    int t = __builtin_amdgcn_update_dpp(0, __float_as_int(v), CTRL, RMASK, 0xf, true);
    return v + __int_as_float(t);
}
__device__ __forceinline__ float wave_sum64(float v) {
    v = dpp_add<0x111, 0xf>(v);   // row_shr:1
    v = dpp_add<0x112, 0xf>(v);   // row_shr:2
    v = dpp_add<0x114, 0xf>(v);   // row_shr:4
    v = dpp_add<0x118, 0xf>(v);   // row_shr:8
    v = dpp_add<0x142, 0xa>(v);   // row_bcast:15
    v = dpp_add<0x143, 0xc>(v);   // row_bcast:31 -> lane63 has total
    return __int_as_float(__builtin_amdgcn_readlane(__float_as_int(v), 63));
}
__device__ __forceinline__ int rdlane_i(int v, int l) {
    return __builtin_amdgcn_readlane(v, l);
}

// f16 pair dot: D = a.lo*b.lo + a.hi*b.hi + c  (V_DOT2_F32_F16, 1 instr)
__device__ __forceinline__ float fdot2(h2 a, h2 b, float c) {
#if __has_builtin(__builtin_amdgcn_fdot2)
    return __builtin_amdgcn_fdot2(a, b, c, false);
#else
    return fmaf((float)a.x, (float)b.x, fmaf((float)a.y, (float)b.y, c));
#endif
}

__device__ __forceinline__ h2 pkrtz(float lo, float hi) {
    return __builtin_amdgcn_cvt_pkrtz(lo, hi);
}

// ---- fused: one wave per (g,s); rows b = g*16..g*16+15 ----
// R14 = R13 with the h2 type fixed (__fp16 vector, matching cvt_pkrtz/fdot2).
// Structure: zero VMEM loads in the t-loop, no inter-wave coupling; GEMM inner
// loop on V_DOT2_F32_F16: W packed f16 ALONG K (64 VGPR), x packed f16 pairs
// once per wave. Per row: 8 readlane + 64 fdot2 (~260 issue cyc) vs R12's
// 16 readlane + 64 shift + 128 fma (~500 cyc).
// LB(256,2): cap 128 VGPR == 4 waves/SIMD guaranteed; natural need ~118 so no
// spill (R4/R11 spilled because cap was 84/64 against ~190 need).
__global__ __launch_bounds__(256, 2) void fused_kernel(
    const float* __restrict__ x, const float* __restrict__ W,
    const float* __restrict__ emb, const float* __restrict__ bsum,
    const float* __restrict__ gamma, const float* __restrict__ beta,
    float* __restrict__ out)
{
    const int lane = threadIdx.x & 63;
    const int wid  = (blockIdx.x << 2) | (threadIdx.x >> 6);   // 0..8191
    const int s    = wid & (Sc - 1);
    const int g    = wid >> 10;                                // 0..7
    const int h0 = lane * 4, h1 = h0 + 256;

    // W panel packed along K: wp[kpair][col] ; 8 cols/lane x 8 kpairs = 64 VGPR
    h2 wp[8][8];
#pragma unroll
    for (int j = 0; j < 8; ++j) {
        const float4 a0 = *reinterpret_cast<const float4*>(&W[(2 * j    ) * Hc + h0]);
        const float4 a1 = *reinterpret_cast<const float4*>(&W[(2 * j + 1) * Hc + h0]);
        const float4 b0 = *reinterpret_cast<const float4*>(&W[(2 * j    ) * Hc + h1]);
        const float4 b1 = *reinterpret_cast<const float4*>(&W[(2 * j + 1) * Hc + h1]);
        wp[j][0] = pkrtz(a0.x, a1.x);
        wp[j][1] = pkrtz(a0.y, a1.y);
        wp[j][2] = pkrtz(a0.z, a1.z);
        wp[j][3] = pkrtz(a0.w, a1.w);
        wp[j][4] = pkrtz(b0.x, b1.x);
        wp[j][5] = pkrtz(b0.y, b1.y);
        wp[j][6] = pkrtz(b0.z, b1.z);
        wp[j][7] = pkrtz(b0.w, b1.w);
    }

    // x for all 16 rows: 4 gather loads, then pack f16 K-pairs via DPP neighbor.
    // xq[q] lane l holds x[b = g*16 + q*4 + (l>>4)][s][l&15].
    const int sub = lane >> 4, i16 = lane & 15;
    int xp0, xp1, xp2, xp3;   // packed (x[2j], x[2j+1]) valid at even i16 lanes
    {
        const size_t xoff = (size_t)s * Fc + i16;
        float q0 = __builtin_nontemporal_load(&x[(size_t)(g * 16 +  0 + sub) * Sc * Fc + xoff]);
        float q1 = __builtin_nontemporal_load(&x[(size_t)(g * 16 +  4 + sub) * Sc * Fc + xoff]);
        float q2 = __builtin_nontemporal_load(&x[(size_t)(g * 16 +  8 + sub) * Sc * Fc + xoff]);
        float q3 = __builtin_nontemporal_load(&x[(size_t)(g * 16 + 12 + sub) * Sc * Fc + xoff]);
        // neighbor (lane+1 within row16) via DPP row_shl:1
        auto nb = [](float v) {
            return __int_as_float(__builtin_amdgcn_update_dpp(
                0, __float_as_int(v), 0x101, 0xf, 0xf, true));
        };
        xp0 = __builtin_bit_cast(int, pkrtz(q0, nb(q0)));
        xp1 = __builtin_bit_cast(int, pkrtz(q1, nb(q1)));
        xp2 = __builtin_bit_cast(int, pkrtz(q2, nb(q2)));
        xp3 = __builtin_bit_cast(int, pkrtz(q3, nb(q3)));
    }

    // loop-invariant per-wave vectors
    const float4 g0  = *reinterpret_cast<const float4*>(&gamma[h0]);
    const float4 g1  = *reinterpret_cast<const float4*>(&gamma[h1]);
    const float4 be0 = *reinterpret_cast<const float4*>(&beta[h0]);
    const float4 be1 = *reinterpret_cast<const float4*>(&beta[h1]);
    float4 ebs0, ebs1;
    {
        const float4 e0  = *reinterpret_cast<const float4*>(&emb[(size_t)s * Hc + h0]);
        const float4 e1  = *reinterpret_cast<const float4*>(&emb[(size_t)s * Hc + h1]);
        const float4 bs0 = *reinterpret_cast<const float4*>(&bsum[h0]);
        const float4 bs1 = *reinterpret_cast<const float4*>(&bsum[h1]);
        ebs0.x = e0.x + bs0.x; ebs0.y = e0.y + bs0.y; ebs0.z = e0.z + bs0.z; ebs0.w = e0.w + bs0.w;
        ebs1.x = e1.x + bs1.x; ebs1.y = e1.y + bs1.y; ebs1.z = e1.z + bs1.z; ebs1.w = e1.w + bs1.w;
    }

#pragma unroll
    for (int t = 0; t < RPW; ++t) {
        const int xsrc = (t >> 2) == 0 ? xp0 : (t >> 2) == 1 ? xp1 : (t >> 2) == 2 ? xp2 : xp3;

        // pure-register dot chain: 8 kpairs x 8 cols = 64 fdot2
        float4 a0 = ebs0, a1 = ebs1;
#pragma unroll
        for (int j = 0; j < 8; ++j) {
            const h2 xj = __builtin_bit_cast(h2, rdlane_i(xsrc, (t & 3) * 16 + 2 * j));
            a0.x = fdot2(xj, wp[j][0], a0.x);
            a0.y = fdot2(xj, wp[j][1], a0.y);
            a0.z = fdot2(xj, wp[j][2], a0.z);
            a0.w = fdot2(xj, wp[j][3], a0.w);
            a1.x = fdot2(xj, wp[j][4], a1.x);
            a1.y = fdot2(xj, wp[j][5], a1.y);
            a1.z = fdot2(xj, wp[j][6], a1.z);
            a1.w = fdot2(xj, wp[j][7], a1.w);
        }

        float psum = a0.x + a0.y + a0.z + a0.w + a1.x + a1.y + a1.z + a1.w;
        float pssq = fmaf(a0.x, a0.x, fmaf(a0.y, a0.y, fmaf(a0.z, a0.z, a0.w * a0.w)));
        pssq = fmaf(a1.x, a1.x, fmaf(a1.y, a1.y, fmaf(a1.z, a1.z, fmaf(a1.w, a1.w, pssq))));

        const float sum = wave_sum64(psum);
        const float ssq = wave_sum64(pssq);

        const float mean = sum * (1.0f / 512.0f);
        const float var  = ssq * (1.0f / 512.0f) - mean * mean;
        const float rs   = rsqrtf(var + LN_EPS);
        const float nmrs = -mean * rs;   // (a-mean)*rs == fma(a, rs, nmrs)

        float4 r0, r1;
        r0.x = fmaf(fmaf(a0.x, rs, nmrs), g0.x, be0.x);
        r0.y = fmaf(fmaf(a0.y, rs, nmrs), g0.y, be0.y);
        r0.z = fmaf(fmaf(a0.z, rs, nmrs), g0.z, be0.z);
        r0.w = fmaf(fmaf(a0.w, rs, nmrs), g0.w, be0.w);
        r1.x = fmaf(fmaf(a1.x, rs, nmrs), g1.x, be1.x);
        r1.y = fmaf(fmaf(a1.y, rs, nmrs), g1.y, be1.y);
        r1.z = fmaf(fmaf(a1.z, rs, nmrs), g1.z, be1.z);
        r1.w = fmaf(fmaf(a1.w, rs, nmrs), g1.w, be1.w);

        float* orow = out + ((size_t)(g * 16 + t) * Sc + s) * Hc;
        *reinterpret_cast<float4*>(&orow[h0]) = r0;
        *reinterpret_cast<float4*>(&orow[h1]) = r1;
    }
}

extern "C" void kernel_launch(void* const* d_in, const int* in_sizes, int n_in,
                              void* d_out, int out_size, void* d_ws, size_t ws_size,
                              hipStream_t stream) {
    const float* x     = (const float*)d_in[0];
    const float* W     = (const float*)d_in[1];
    const float* b     = (const float*)d_in[2];
    const float* emb   = (const float*)d_in[3];
    const float* gamma = (const float*)d_in[4];
    const float* beta  = (const float*)d_in[5];
    float* out  = (float*)d_out;
    float* bsum = (float*)d_ws;     // 512 floats

    bsum_kernel<<<Hc / 64, 64, 0, stream>>>(b, bsum);

    const int blocks = (8 * Sc) / 4;   // 8192 waves, 4 per block
    fused_kernel<<<blocks, 256, 0, stream>>>(x, W, emb, bsum, gamma, beta, out);
}